// Round 8
// baseline (141.887 us; speedup 1.0000x reference)
//
#include <hip/hip_runtime.h>

// MaskPatchClassificationHead — B=4, P=256, F=512
// 2-node graph (no grid barriers — measured R5: memory-polled barriers cost far
// more than the ~7us/node dispatch overhead they save on MI355X):
//   node A: fc_sig    — fc partial GEMM (K-split 2) + label sigs + acc/done init
//   node B: score_loss — GEMM-style scores in registers (thread owns q column;
//           measured R6: cross-lane-reduction dots are latency-bound at 4
//           waves/CU), then softmax/KL, atomicAdd, done-count finalize.
// R7 bug fixed: XOR swizzle was applied to BOTH the read address and the
// logical k index (double-XOR). Physical slot = k4 ^ myswz; logical = k4.

#define INV_TAU (1.0f / 0.07f)
#define EPSC 1e-5f

constexpr int Bz = 4;
constexpr int Pn = 256;
constexpr int Fdim = 512;
constexpr int Mrows = Bz * Pn;                       // 1024
constexpr size_t HP_STRIDE = (size_t)Mrows * Fdim;   // per fc K-half partial

__device__ __forceinline__ float wave_sum(float v) {
  #pragma unroll
  for (int o = 32; o > 0; o >>= 1) v += __shfl_down(v, o, 64);
  return v;
}
__device__ __forceinline__ float wave_max(float v) {
  #pragma unroll
  for (int o = 32; o > 0; o >>= 1) v = fmaxf(v, __shfl_down(v, o, 64));
  return v;
}
__device__ __forceinline__ unsigned long long mix64(unsigned long long z) {
  z ^= z >> 33; z *= 0xff51afd7ed558ccdULL;
  z ^= z >> 33; z *= 0xc4ceb9fe1a85ec53ULL;
  z ^= z >> 33; return z;
}

// ---------------- node A: fc partial GEMM + label sigs + init (round-6 proven)
// hp[z][m][n] = sum_{k in half z} A[m][k] W[n][k]
// 64x64 tile, 4x4 micro, BK=32, 256 threads. grid (16,8,2) = 256 blocks.
__global__ __launch_bounds__(256) void fc_sig(const float* __restrict__ A,
                                              const float* __restrict__ W,
                                              const float* __restrict__ labels,
                                              float* __restrict__ hp,
                                              ulonglong2* __restrict__ sig,
                                              float* __restrict__ acc,
                                              unsigned int* __restrict__ done) {
  const int t = threadIdx.x;
  const int bid = blockIdx.x + 16 * (blockIdx.y + 8 * blockIdx.z);
  if (bid == 0 && t == 0) { acc[0] = 0.0f; done[0] = 0u; }

  // --- label signatures: 4 rows/block, one 64-lane group per row
  {
    const int g = t >> 6, lane = t & 63;
    const int row = bid * 4 + g;
    const uint4* l4 = (const uint4*)(labels + (size_t)row * Fdim);
    unsigned long long h1 = 0, h2 = 0;
    #pragma unroll
    for (int c = lane; c < Fdim / 4; c += 64) {
      uint4 w = l4[c];
      unsigned long long w01 = ((unsigned long long)w.y << 32) | w.x;
      unsigned long long w23 = ((unsigned long long)w.w << 32) | w.z;
      unsigned long long idx = (unsigned long long)c;
      h1 ^= mix64(w01 + idx * 0x9E3779B97F4A7C15ULL + 0x0123456789ABCDEFULL);
      h1 ^= mix64(w23 + idx * 0xC2B2AE3D27D4EB4FULL + 1ULL);
      h2 ^= mix64(w01 ^ (idx * 0x165667B19E3779F9ULL + 7ULL));
      h2 ^= mix64(w23 ^ (idx * 0x27D4EB2F165667C5ULL + 13ULL));
    }
    #pragma unroll
    for (int o = 32; o > 0; o >>= 1) {
      h1 ^= __shfl_down(h1, o, 64);
      h2 ^= __shfl_down(h2, o, 64);
    }
    if (lane == 0) { sig[row].x = h1; sig[row].y = h2; }
  }

  // --- fc GEMM
  const int m0 = blockIdx.x * 64, n0 = blockIdx.y * 64;
  const int kbase = blockIdx.z * 256;
  float* C = hp + (size_t)blockIdx.z * HP_STRIDE;
  __shared__ float Ash[32][68];  // [k][m] transposed
  __shared__ float Bsh[32][68];  // [k][n]
  const int tx = t & 15, ty = t >> 4;
  const int r0 = t >> 3, c0 = (t & 7) << 2;
  float a4[4][4] = {};

  for (int kc = 0; kc < 256; kc += 32) {
    const float* Ap = A + (size_t)(m0 + r0) * Fdim + kbase + kc + c0;
    const float* Wp = W + (size_t)(n0 + r0) * Fdim + kbase + kc + c0;
    float4 a0 = *(const float4*)Ap;
    float4 a1 = *(const float4*)(Ap + 32 * Fdim);
    float4 b0 = *(const float4*)Wp;
    float4 b1 = *(const float4*)(Wp + 32 * Fdim);
    __syncthreads();
    Ash[c0+0][r0] = a0.x; Ash[c0+1][r0] = a0.y; Ash[c0+2][r0] = a0.z; Ash[c0+3][r0] = a0.w;
    Ash[c0+0][r0+32] = a1.x; Ash[c0+1][r0+32] = a1.y; Ash[c0+2][r0+32] = a1.z; Ash[c0+3][r0+32] = a1.w;
    Bsh[c0+0][r0] = b0.x; Bsh[c0+1][r0] = b0.y; Bsh[c0+2][r0] = b0.z; Bsh[c0+3][r0] = b0.w;
    Bsh[c0+0][r0+32] = b1.x; Bsh[c0+1][r0+32] = b1.y; Bsh[c0+2][r0+32] = b1.z; Bsh[c0+3][r0+32] = b1.w;
    __syncthreads();
    #pragma unroll 8
    for (int k = 0; k < 32; ++k) {
      float4 av = *(const float4*)&Ash[k][ty << 2];
      float4 bv = *(const float4*)&Bsh[k][tx << 2];
      a4[0][0] = fmaf(av.x, bv.x, a4[0][0]); a4[0][1] = fmaf(av.x, bv.y, a4[0][1]);
      a4[0][2] = fmaf(av.x, bv.z, a4[0][2]); a4[0][3] = fmaf(av.x, bv.w, a4[0][3]);
      a4[1][0] = fmaf(av.y, bv.x, a4[1][0]); a4[1][1] = fmaf(av.y, bv.y, a4[1][1]);
      a4[1][2] = fmaf(av.y, bv.z, a4[1][2]); a4[1][3] = fmaf(av.y, bv.w, a4[1][3]);
      a4[2][0] = fmaf(av.z, bv.x, a4[2][0]); a4[2][1] = fmaf(av.z, bv.y, a4[2][1]);
      a4[2][2] = fmaf(av.z, bv.z, a4[2][2]); a4[2][3] = fmaf(av.z, bv.w, a4[2][3]);
      a4[3][0] = fmaf(av.w, bv.x, a4[3][0]); a4[3][1] = fmaf(av.w, bv.y, a4[3][1]);
      a4[3][2] = fmaf(av.w, bv.z, a4[3][2]); a4[3][3] = fmaf(av.w, bv.w, a4[3][3]);
    }
  }
  #pragma unroll
  for (int i = 0; i < 4; ++i) {
    float4 o; o.x = a4[i][0]; o.y = a4[i][1]; o.z = a4[i][2]; o.w = a4[i][3];
    *(float4*)(C + (size_t)(m0 + (ty << 2) + i) * Fdim + n0 + (tx << 2)) = o;
  }
}

// ---------------- node B: GEMM-style scores + loss.
// grid 256 = (b = bid>>6, p0 = (bid&63)*4), 256 threads; thread t owns q=t.
// k-tiles of 32 staged into LDS with XOR-swizzled float4 slots (spreads both
// staged writes and per-thread-row reads across banks). Dots + norm^2 in regs.
__global__ __launch_bounds__(256) void score_loss(const float* __restrict__ hp,
                                                  const float* __restrict__ bias,
                                                  const ulonglong2* __restrict__ sig,
                                                  const float* __restrict__ labels,
                                                  float* __restrict__ acc,
                                                  unsigned int* __restrict__ done,
                                                  float* __restrict__ out) {
  const int bid = blockIdx.x;
  const int b = bid >> 6, p0 = (bid & 63) * 4;
  const int t = threadIdx.x;

  // buf: hqS [256 rows][32 floats, 8 xor-swizzled float4 slots] = 32 KB
  //      hpS [4][520] (4 combined p-rows, padded)               = 8.3 KB
  __shared__ float buf[256 * 32 + 4 * 520];
  float* hqS = buf;
  float* hpS = buf + 256 * 32;

  const float* h0 = hp;
  const float* h1 = hp + HP_STRIDE;

  // --- stage h_p rows (combined hp0+hp1+bias): 512 float4 slots, 2 per thread
  #pragma unroll
  for (int j = 0; j < 2; ++j) {
    const int f = j * 256 + t;          // 0..511
    const int g = f >> 7, k4 = f & 127;
    const size_t off = (size_t)((b << 8) + p0 + g) * Fdim + (k4 << 2);
    float4 x = *(const float4*)(h0 + off);
    float4 y = *(const float4*)(h1 + off);
    float4 bi = *(const float4*)(bias + (k4 << 2));
    float4 v;
    v.x = x.x + y.x + bi.x; v.y = x.y + y.y + bi.y;
    v.z = x.z + y.z + bi.z; v.w = x.w + y.w + bi.w;
    *(float4*)&hpS[g * 520 + (k4 << 2)] = v;
  }

  float a0 = 0.f, a1 = 0.f, a2 = 0.f, a3 = 0.f, n2 = 0.f;
  const int sr = t >> 3;            // staging row within pass (0..31)
  const int ss = t & 7;             // staging float4 slot (0..7)
  const int myswz = t & 7;          // own-row swizzle key (row t: t&7)

  for (int kt = 0; kt < 16; ++kt) {
    const int kb = kt << 5;
    const float4 bi = *(const float4*)(bias + kb + (ss << 2));
    __syncthreads();  // previous tile's reads complete
    #pragma unroll
    for (int ps = 0; ps < 8; ++ps) {
      const int r = (ps << 5) + sr;
      const size_t off = (size_t)((b << 8) + r) * Fdim + kb + (ss << 2);
      float4 x = *(const float4*)(h0 + off);
      float4 y = *(const float4*)(h1 + off);
      float4 v;
      v.x = x.x + y.x + bi.x; v.y = x.y + y.y + bi.y;
      v.z = x.z + y.z + bi.z; v.w = x.w + y.w + bi.w;
      // logical slot ss of row r -> physical slot ss ^ (r&7)
      *(float4*)&hqS[(r << 5) + ((ss ^ (r & 7)) << 2)] = v;
    }
    __syncthreads();
    #pragma unroll
    for (int k4 = 0; k4 < 8; ++k4) {
      // physical slot k4 ^ myswz of own row t holds LOGICAL slot k4
      float4 o = *(const float4*)&hqS[(t << 5) + ((k4 ^ myswz) << 2)];
      const int kk = kb + (k4 << 2);  // logical k offset (R7 fix: was ^myswz)
      n2 = fmaf(o.x, o.x, fmaf(o.y, o.y, fmaf(o.z, o.z, fmaf(o.w, o.w, n2))));
      float4 q0 = *(const float4*)&hpS[0 * 520 + kk];
      float4 q1 = *(const float4*)&hpS[1 * 520 + kk];
      float4 q2 = *(const float4*)&hpS[2 * 520 + kk];
      float4 q3 = *(const float4*)&hpS[3 * 520 + kk];
      a0 = fmaf(o.x, q0.x, fmaf(o.y, q0.y, fmaf(o.z, q0.z, fmaf(o.w, q0.w, a0))));
      a1 = fmaf(o.x, q1.x, fmaf(o.y, q1.y, fmaf(o.z, q1.z, fmaf(o.w, q1.w, a1))));
      a2 = fmaf(o.x, q2.x, fmaf(o.y, q2.y, fmaf(o.z, q2.z, fmaf(o.w, q2.w, a2))));
      a3 = fmaf(o.x, q3.x, fmaf(o.y, q3.y, fmaf(o.z, q3.z, fmaf(o.w, q3.w, a3))));
    }
  }
  __syncthreads();  // hqS reads done; overlay loss arrays

  float* invn = buf;        // 256 floats
  float* red  = buf + 256;  // 12 floats
  invn[t] = 1.0f / fmaxf(sqrtf(n2), 1e-12f);
  const ulonglong2 sq = sig[(b << 8) + t];
  __syncthreads();

  const float accs[4] = {a0, a1, a2, a3};
  const int q = t;
  float lane_contrib = 0.0f;
  #pragma unroll
  for (int g = 0; g < 4; ++g) {
    const int p = p0 + g;
    float s = accs[g] * invn[p] * invn[q] * INV_TAU;

    // exact row equality <=> L1 dist == 0. sig mismatch => unequal;
    // sig match with q!=p => exact verify (cold path).
    ulonglong2 sp = sig[(b << 8) + p];
    bool eq;
    if (q == p) eq = true;
    else if (sp.x == sq.x && sp.y == sq.y) {
      bool v = true;
      const float* lp = labels + (size_t)((b << 8) + p) * Fdim;
      const float* lq = labels + (size_t)((b << 8) + q) * Fdim;
      for (int j = 0; j < Fdim; ++j) v = v && (lp[j] == lq[j]);
      eq = v;
    } else eq = false;

    float m = wave_max(s);
    if ((q & 63) == 0) red[q >> 6] = m;
    __syncthreads();
    m = fmaxf(fmaxf(red[0], red[1]), fmaxf(red[2], red[3]));

    float e = expf(s - m);
    float zc = wave_sum(e);
    float cc = wave_sum(eq ? 1.0f : 0.0f);
    if ((q & 63) == 0) { red[4 + (q >> 6)] = zc; red[8 + (q >> 6)] = cc; }
    __syncthreads();
    float z = red[4] + red[5] + red[6] + red[7];
    float n = red[8] + red[9] + red[10] + red[11];

    float prob = fminf(fmaxf(e / z, EPSC), 1.0f - EPSC);
    if (eq) lane_contrib += (-logf(n) - logf(prob)) / n;
    __syncthreads();  // red reused next iteration
  }

  float c = wave_sum(lane_contrib);
  if ((t & 63) == 0) red[t >> 6] = c;
  __syncthreads();
  if (t == 0) {
    atomicAdd(acc, red[0] + red[1] + red[2] + red[3]);
    __threadfence();
    unsigned int v = atomicAdd(done, 1u);
    if (v == 255u) {  // last of 256 blocks: all acc adds visible
      float tot = atomicAdd(acc, 0.0f);
      out[0] = tot * (1.0f / (float)(Bz * Pn));
    }
  }
}

extern "C" void kernel_launch(void* const* d_in, const int* in_sizes, int n_in,
                              void* d_out, int out_size, void* d_ws, size_t ws_size,
                              hipStream_t stream) {
  const float* inputs = (const float*)d_in[0];
  const float* labels = (const float*)d_in[1];
  const float* W      = (const float*)d_in[2];
  const float* bias   = (const float*)d_in[3];
  float* out = (float*)d_out;

  char* ws = (char*)d_ws;
  float* acc         = (float*)ws;                       // 4 B (init by node A)
  unsigned int* done = (unsigned int*)(ws + 4);          // 4 B (init by node A)
  float* hp = (float*)(ws + 256);                        // 2 * 2 MB fc partials
  ulonglong2* sig = (ulonglong2*)(ws + 256 + 2 * HP_STRIDE * 4);  // 16 KB

  fc_sig<<<dim3(16, 8, 2), 256, 0, stream>>>(inputs, W, labels, hp, sig, acc, done);
  score_loss<<<256, 256, 0, stream>>>(hp, bias, sig, labels, acc, done, out);
}